// Round 1
// baseline (369.823 us; speedup 1.0000x reference)
//
#include <hip/hip_runtime.h>

typedef short bf16x8 __attribute__((ext_vector_type(8)));
typedef float f32x4 __attribute__((ext_vector_type(4)));
typedef unsigned short ushort_t;
typedef unsigned int uint_t;

#define DIM 2048
#define NH 16
#define HD 128

__device__ __forceinline__ ushort_t f2b(float f) {
    union { float f; uint_t u; } a; a.f = f;
    uint_t u = a.u;
    return (ushort_t)((u + 0x7fffu + ((u >> 16) & 1u)) >> 16);
}

__device__ __forceinline__ void gload_lds16(const void* g, void* l) {
    void* gg = const_cast<void*>(g);
    __builtin_amdgcn_global_load_lds(
        (__attribute__((address_space(1))) uint_t*)gg,
        (__attribute__((address_space(3))) uint_t*)l, 16, 0, 0);
}

// ---------------- fp32 -> bf16 convert ----------------
__global__ __launch_bounds__(256) void k_cvt(const float* __restrict__ in,
                                             ushort_t* __restrict__ out, int n) {
    int idx = (blockIdx.x * 256 + threadIdx.x) * 8;
    if (idx >= n) return;
    float4 a = *(const float4*)(in + idx);
    float4 b = *(const float4*)(in + idx + 4);
    uint4 o;
    o.x = (uint_t)f2b(a.x) | ((uint_t)f2b(a.y) << 16);
    o.y = (uint_t)f2b(a.z) | ((uint_t)f2b(a.w) << 16);
    o.z = (uint_t)f2b(b.x) | ((uint_t)f2b(b.y) << 16);
    o.w = (uint_t)f2b(b.z) | ((uint_t)f2b(b.w) << 16);
    *(uint4*)(out + idx) = o;
}

// ---------------- bf16 NT GEMM: out = A(MxK) * B(NxK)^T + bias ----------------
struct GemmArgs {
    const ushort_t* A;
    const ushort_t* B;
    const float* bias;
    void* out;
};

__global__ __launch_bounds__(256) void k_gemm_bt(GemmArgs a0, GemmArgs a1,
                                                 int M, int N, int K, int out_bf16) {
    __shared__ ushort_t lA[128 * 32];
    __shared__ ushort_t lB[128 * 32];
    GemmArgs ar = blockIdx.z ? a1 : a0;
    int tid = threadIdx.x;
    int lane = tid & 63, wid = tid >> 6;
    int wr = wid >> 1, wc = wid & 1;
    int bm = blockIdx.x, bn = blockIdx.y;

    f32x4 acc[4][4];
#pragma unroll
    for (int m = 0; m < 4; m++)
#pragma unroll
        for (int n = 0; n < 4; n++) acc[m][n] = (f32x4){0.f, 0.f, 0.f, 0.f};

    const ushort_t* ga = ar.A + (size_t)(bm * 128 + wid * 32 + (lane >> 2)) * K + (lane & 3) * 8;
    const ushort_t* gb = ar.B + (size_t)(bn * 128 + wid * 32 + (lane >> 2)) * K + (lane & 3) * 8;
    ushort_t* la0 = lA + wid * 32 * 32;
    ushort_t* lb0 = lB + wid * 32 * 32;
    int r = lane & 15, kq = (lane >> 4) * 8;
    int Kt = K >> 5;

    for (int kt = 0; kt < Kt; ++kt) {
        __syncthreads();
        gload_lds16(ga, la0);
        gload_lds16(ga + 16 * (size_t)K, la0 + 16 * 32);
        gload_lds16(gb, lb0);
        gload_lds16(gb + 16 * (size_t)K, lb0 + 16 * 32);
        ga += 32; gb += 32;
        __syncthreads();
        bf16x8 af[4], bfr[4];
#pragma unroll
        for (int m = 0; m < 4; m++)
            af[m] = *(const bf16x8*)(lA + (wr * 64 + m * 16 + r) * 32 + kq);
#pragma unroll
        for (int n = 0; n < 4; n++)
            bfr[n] = *(const bf16x8*)(lB + (wc * 64 + n * 16 + r) * 32 + kq);
#pragma unroll
        for (int m = 0; m < 4; m++)
#pragma unroll
            for (int n = 0; n < 4; n++)
                acc[m][n] = __builtin_amdgcn_mfma_f32_16x16x32_bf16(af[m], bfr[n], acc[m][n], 0, 0, 0);
    }

#pragma unroll
    for (int n = 0; n < 4; n++) {
        int col = bn * 128 + wc * 64 + n * 16 + (lane & 15);
        float bv = ar.bias[col];
#pragma unroll
        for (int m = 0; m < 4; m++) {
            int row0 = bm * 128 + wr * 64 + m * 16 + (lane >> 4) * 4;
#pragma unroll
            for (int q = 0; q < 4; q++) {
                float v = acc[m][n][q] + bv;
                size_t o = (size_t)(row0 + q) * N + col;
                if (out_bf16) ((ushort_t*)ar.out)[o] = f2b(v);
                else ((float*)ar.out)[o] = v;
            }
        }
    }
}

// ---------------- fused RMSNorm + RoPE, fp32 in, bf16 out ----------------
__global__ __launch_bounds__(256) void k_rms_rope(const float* __restrict__ in,
                                                  const float* __restrict__ gain,
                                                  const float* __restrict__ freqs,
                                                  ushort_t* __restrict__ out,
                                                  int S, float oscale) {
    int row = blockIdx.x;
    int s = row % S;
    int tid = threadIdx.x;
    const float* p = in + (size_t)row * DIM + tid * 8;
    float4 a = *(const float4*)p;
    float4 b = *(const float4*)(p + 4);
    float y[8] = {a.x, a.y, a.z, a.w, b.x, b.y, b.z, b.w};
    float ss = 0.f;
#pragma unroll
    for (int j = 0; j < 8; j++) ss += y[j] * y[j];
#pragma unroll
    for (int off = 32; off > 0; off >>= 1) ss += __shfl_xor(ss, off, 64);
    __shared__ float red[4];
    int lane = tid & 63, wid = tid >> 6;
    if (lane == 0) red[wid] = ss;
    __syncthreads();
    float tot = red[0] + red[1] + red[2] + red[3];
    float inv = rsqrtf(tot * (1.0f / DIM) + 1e-6f);
    const float* g = gain + tid * 8;
    float4 g0 = *(const float4*)g;
    float4 g1 = *(const float4*)(g + 4);
    float gg[8] = {g0.x, g0.y, g0.z, g0.w, g1.x, g1.y, g1.z, g1.w};
    int p0 = (tid * 8 & 127) >> 1;
    const float* fq = freqs + ((size_t)s * 64 + p0) * 2;
    uint_t ow[4];
#pragma unroll
    for (int j = 0; j < 4; j++) {
        float fr = fq[j * 2 + 0], fi = fq[j * 2 + 1];
        float xr = y[2 * j] * inv * gg[2 * j];
        float xi = y[2 * j + 1] * inv * gg[2 * j + 1];
        float o0 = (xr * fr - xi * fi) * oscale;
        float o1 = (xr * fi + xi * fr) * oscale;
        ow[j] = (uint_t)f2b(o0) | ((uint_t)f2b(o1) << 16);
    }
    *(uint4*)(out + (size_t)row * DIM + tid * 8) = make_uint4(ow[0], ow[1], ow[2], ow[3]);
}

// ---------------- V transpose: vcam/vren (rows, DIM) -> vt[b,h,d=128,kv=1024] ----------------
__global__ __launch_bounds__(256) void k_vt(const ushort_t* __restrict__ vcam,
                                            const ushort_t* __restrict__ vren,
                                            ushort_t* __restrict__ vt) {
    __shared__ ushort_t t[64 * 136];
    int kt = blockIdx.x, h = blockIdx.y, b = blockIdx.z;
    int kv0 = kt * 64;
    const ushort_t* src = (kv0 < 512)
        ? vcam + ((size_t)(b * 512 + kv0)) * DIM + h * HD
        : vren + ((size_t)(b * 512 + kv0 - 512)) * DIM + h * HD;
    int tid = threadIdx.x;
#pragma unroll
    for (int i = 0; i < 4; i++) {
        int idx = i * 256 + tid;
        int kv = idx >> 4, c8 = idx & 15;
        uint4 v = *(const uint4*)(src + (size_t)kv * DIM + c8 * 8);
        *(uint4*)(t + kv * 136 + c8 * 8) = v;
    }
    __syncthreads();
    ushort_t* dst = vt + ((size_t)((b * NH + h) * HD)) * 1024 + kv0;
#pragma unroll
    for (int i = 0; i < 4; i++) {
        int idx = i * 256 + tid;
        int d = idx >> 3, c8 = idx & 7;
        ushort_t tmp[8];
#pragma unroll
        for (int j = 0; j < 8; j++) tmp[j] = t[(c8 * 8 + j) * 136 + d];
        uint4 o;
        o.x = (uint_t)tmp[0] | ((uint_t)tmp[1] << 16);
        o.y = (uint_t)tmp[2] | ((uint_t)tmp[3] << 16);
        o.z = (uint_t)tmp[4] | ((uint_t)tmp[5] << 16);
        o.w = (uint_t)tmp[6] | ((uint_t)tmp[7] << 16);
        *(uint4*)(dst + (size_t)d * 1024 + c8 * 8) = o;
    }
}

// ---------------- flash attention: Q(4096,2048) x K/V (1024 kv) -> O bf16 ----------------
__global__ __launch_bounds__(256) void k_attn(const ushort_t* __restrict__ Q,
                                              const ushort_t* __restrict__ Kc,
                                              const ushort_t* __restrict__ Kr,
                                              const ushort_t* __restrict__ Vt,
                                              ushort_t* __restrict__ O) {
    __shared__ ushort_t lK[64 * 128];      // [kv=64][d=128], rows XOR-swizzled
    __shared__ ushort_t lV[128 * 64];      // [d=128][kv=64], rows XOR-swizzled
    __shared__ ushort_t lP[4][16 * 72];    // per-wave P, padded stride 72
    int tid = threadIdx.x, lane = tid & 63, wid = tid >> 6;
    int qt = blockIdx.x, h = blockIdx.y, b = blockIdx.z;
    int q0 = qt * 64 + wid * 16;

    const ushort_t* qg = Q + ((size_t)(b * 2048 + q0 + (lane & 15))) * DIM + h * HD + (lane >> 4) * 8;
    bf16x8 aQ[4];
#pragma unroll
    for (int ks = 0; ks < 4; ks++) aQ[ks] = *(const bf16x8*)(qg + ks * 32);

    float mr[4], lr[4];
#pragma unroll
    for (int r = 0; r < 4; r++) { mr[r] = -1e30f; lr[r] = 0.f; }
    f32x4 o[8];
#pragma unroll
    for (int d = 0; d < 8; d++) o[d] = (f32x4){0, 0, 0, 0};

    ushort_t* lPw = lP[wid];

    for (int kvt = 0; kvt < 16; ++kvt) {
        __syncthreads();
        int kv0 = kvt * 64;
        const ushort_t* kg = (kv0 < 512)
            ? Kc + ((size_t)(b * 512 + kv0)) * DIM + h * HD
            : Kr + ((size_t)(b * 512 + kv0 - 512)) * DIM + h * HD;
#pragma unroll
        for (int c = 0; c < 4; c++) {  // K: 4 rows per call (256B rows)
            int lrow = wid * 16 + c * 4 + (lane >> 4);
            int srcoff = ((lane & 15) * 16) ^ ((lrow & 7) << 4);
            gload_lds16((const char*)kg + (size_t)lrow * DIM * 2 + srcoff,
                        lK + (wid * 16 + c * 4) * 128);
        }
        const ushort_t* vg = Vt + ((size_t)((b * NH + h) * HD)) * 1024 + kv0;
#pragma unroll
        for (int c = 0; c < 4; c++) {  // Vt: 8 rows per call (128B rows)
            int vrow = wid * 32 + c * 8 + (lane >> 3);
            int srcoff = ((lane & 7) * 16) ^ ((vrow & 7) << 4);
            gload_lds16((const char*)vg + (size_t)vrow * 1024 * 2 + srcoff,
                        lV + (wid * 32 + c * 8) * 64);
        }
        __syncthreads();

        // S = Q K^T (scale folded into Q)
        f32x4 s[4];
#pragma unroll
        for (int n = 0; n < 4; n++) s[n] = (f32x4){0, 0, 0, 0};
#pragma unroll
        for (int n = 0; n < 4; n++) {
            int kvcol = n * 16 + (lane & 15);
#pragma unroll
            for (int ks = 0; ks < 4; ks++) {
                int byt = (kvcol * 256 + (ks * 32 + (lane >> 4) * 8) * 2) ^ ((kvcol & 7) << 4);
                bf16x8 bK = *(const bf16x8*)((const char*)lK + byt);
                s[n] = __builtin_amdgcn_mfma_f32_16x16x32_bf16(aQ[ks], bK, s[n], 0, 0, 0);
            }
        }

        // online softmax (rows live in 16-lane groups)
#pragma unroll
        for (int r = 0; r < 4; r++) {
            float mx = fmaxf(fmaxf(s[0][r], s[1][r]), fmaxf(s[2][r], s[3][r]));
#pragma unroll
            for (int off = 1; off < 16; off <<= 1) mx = fmaxf(mx, __shfl_xor(mx, off, 64));
            float mn = fmaxf(mr[r], mx);
            float alpha = __expf(mr[r] - mn);
            mr[r] = mn;
            float pvl[4];
            float psum = 0.f;
#pragma unroll
            for (int n = 0; n < 4; n++) { pvl[n] = __expf(s[n][r] - mn); psum += pvl[n]; }
#pragma unroll
            for (int off = 1; off < 16; off <<= 1) psum += __shfl_xor(psum, off, 64);
            lr[r] = lr[r] * alpha + psum;
#pragma unroll
            for (int d = 0; d < 8; d++) o[d][r] *= alpha;
            int prow = (lane >> 4) * 4 + r;
#pragma unroll
            for (int n = 0; n < 4; n++) lPw[prow * 72 + n * 16 + (lane & 15)] = f2b(pvl[n]);
        }
        __syncthreads();

        // O += P V
#pragma unroll
        for (int kk = 0; kk < 2; kk++) {
            bf16x8 aP = *(const bf16x8*)(lPw + (lane & 15) * 72 + kk * 32 + (lane >> 4) * 8);
#pragma unroll
            for (int d = 0; d < 8; d++) {
                int vrow = d * 16 + (lane & 15);
                int byt = (vrow * 128 + (kk * 32 + (lane >> 4) * 8) * 2) ^ ((vrow & 7) << 4);
                bf16x8 bV = *(const bf16x8*)((const char*)lV + byt);
                o[d] = __builtin_amdgcn_mfma_f32_16x16x32_bf16(aP, bV, o[d], 0, 0, 0);
            }
        }
    }

#pragma unroll
    for (int r = 0; r < 4; r++) {
        float inv = 1.0f / lr[r];
        int row = b * 2048 + q0 + (lane >> 4) * 4 + r;
#pragma unroll
        for (int d = 0; d < 8; d++)
            O[(size_t)row * DIM + h * HD + d * 16 + (lane & 15)] = f2b(o[d][r] * inv);
    }
}

extern "C" void kernel_launch(void* const* d_in, const int* in_sizes, int n_in,
                              void* d_out, int out_size, void* d_ws, size_t ws_size,
                              hipStream_t stream) {
    const float* x   = (const float*)d_in[0];
    const float* cam = (const float*)d_in[1];
    const float* ren = (const float*)d_in[2];
    const float* fx  = (const float*)d_in[3];
    const float* fc  = (const float*)d_in[4];
    const float* fr  = (const float*)d_in[5];
    const float* wq  = (const float*)d_in[6];
    const float* bq  = (const float*)d_in[7];
    const float* wk  = (const float*)d_in[8];
    const float* bk  = (const float*)d_in[9];
    const float* wv  = (const float*)d_in[10];
    const float* bv  = (const float*)d_in[11];
    const float* wkr = (const float*)d_in[12];
    const float* bkr = (const float*)d_in[13];
    const float* wvr = (const float*)d_in[14];
    const float* bvr = (const float*)d_in[15];
    const float* wo  = (const float*)d_in[16];
    const float* bo  = (const float*)d_in[17];
    const float* gq  = (const float*)d_in[18];
    const float* gk  = (const float*)d_in[19];

    char* ws = (char*)d_ws;
    ushort_t* wq_b     = (ushort_t*)(ws + 0);
    ushort_t* wk_b     = (ushort_t*)(ws + 8388608);
    ushort_t* wv_b     = (ushort_t*)(ws + 16777216);
    ushort_t* wkr_b    = (ushort_t*)(ws + 25165824);
    ushort_t* wvr_b    = (ushort_t*)(ws + 33554432);
    ushort_t* wo_b     = (ushort_t*)(ws + 41943040);
    ushort_t* xb       = (ushort_t*)(ws + 50331648);   // 16.8MB; reused by attn_bf later
    ushort_t* camb     = (ushort_t*)(ws + 67108864);
    ushort_t* renb     = (ushort_t*)(ws + 71303168);
    float*    kcam_lin = (float*)(ws + 75497472);      // 8.4MB; region reused by vt later
    float*    kren_lin = (float*)(ws + 83886080);
    ushort_t* q_bf     = (ushort_t*)(ws + 92274688);
    ushort_t* kcam_bf  = (ushort_t*)(ws + 109051904);
    ushort_t* kren_bf  = (ushort_t*)(ws + 113246208);
    ushort_t* vcam_bf  = (ushort_t*)(ws + 117440512);
    ushort_t* vren_bf  = (ushort_t*)(ws + 121634816);
    ushort_t* vt       = (ushort_t*)(ws + 75497472);   // overlays dead kcam_lin/kren_lin
    ushort_t* attn_bf  = (ushort_t*)(ws + 50331648);   // overlays dead xb
    float*    q_lin    = (float*)d_out;                // d_out doubles as Q-proj scratch

    // fp32 -> bf16 converts
    k_cvt<<<2048, 256, 0, stream>>>(wq, wq_b, 4194304);
    k_cvt<<<2048, 256, 0, stream>>>(wk, wk_b, 4194304);
    k_cvt<<<2048, 256, 0, stream>>>(wv, wv_b, 4194304);
    k_cvt<<<2048, 256, 0, stream>>>(wkr, wkr_b, 4194304);
    k_cvt<<<2048, 256, 0, stream>>>(wvr, wvr_b, 4194304);
    k_cvt<<<2048, 256, 0, stream>>>(wo, wo_b, 4194304);
    k_cvt<<<4096, 256, 0, stream>>>(x, xb, 8388608);
    k_cvt<<<1024, 256, 0, stream>>>(cam, camb, 2097152);
    k_cvt<<<1024, 256, 0, stream>>>(ren, renb, 2097152);

    // Q projection -> fp32 scratch (d_out), then RMSNorm+RoPE (+1/sqrt(HD)) -> bf16
    GemmArgs gqa{xb, wq_b, bq, (void*)q_lin};
    k_gemm_bt<<<dim3(32, 16, 1), 256, 0, stream>>>(gqa, gqa, 4096, 2048, 2048, 0);
    k_rms_rope<<<4096, 256, 0, stream>>>(q_lin, gq, fx, q_bf, 2048, 0.08838834764831845f);

    // K projections (cam/ren batched in z), RMSNorm+RoPE
    GemmArgs kca{camb, wk_b, bk, (void*)kcam_lin};
    GemmArgs kra{renb, wkr_b, bkr, (void*)kren_lin};
    k_gemm_bt<<<dim3(8, 16, 2), 256, 0, stream>>>(kca, kra, 1024, 2048, 2048, 0);
    k_rms_rope<<<1024, 256, 0, stream>>>(kcam_lin, gk, fc, kcam_bf, 512, 1.0f);
    k_rms_rope<<<1024, 256, 0, stream>>>(kren_lin, gk, fr, kren_bf, 512, 1.0f);

    // V projections straight to bf16, then transpose to [b,h,d,kv]
    GemmArgs vca{camb, wv_b, bv, (void*)vcam_bf};
    GemmArgs vra{renb, wvr_b, bvr, (void*)vren_bf};
    k_gemm_bt<<<dim3(8, 16, 2), 256, 0, stream>>>(vca, vra, 1024, 2048, 2048, 1);
    k_vt<<<dim3(16, 16, 2), 256, 0, stream>>>(vcam_bf, vren_bf, vt);

    // flash attention
    k_attn<<<dim3(32, 16, 2), 256, 0, stream>>>(q_bf, kcam_bf, kren_bf, vt, attn_bf);

    // output projection -> d_out (fp32)
    GemmArgs goa{attn_bf, wo_b, bo, d_out};
    k_gemm_bt<<<dim3(32, 16, 1), 256, 0, stream>>>(goa, goa, 4096, 2048, 2048, 0);
}